// Round 10
// baseline (148.312 us; speedup 1.0000x reference)
//
#include <hip/hip_runtime.h>
#include <stdint.h>

typedef unsigned int uint32;
typedef unsigned long long u64;
typedef short bf16x8 __attribute__((ext_vector_type(8)));
typedef float f32x4 __attribute__((ext_vector_type(4)));

// fp32 -> bf16 bits, round-to-nearest-even
__device__ __forceinline__ unsigned short f2bf(float f) {
  uint32 u = __builtin_bit_cast(uint32, f);
  u += 0x7FFFu + ((u >> 16) & 1u);
  return (unsigned short)(u >> 16);
}

// ---------------------------------------------------------------------------
// K1: h = X*W (16384x128 @ 128x64), e_src/e_dst = h.a, store
//   hTt : bf16, k-blocked layout [B][i>>3][d][i&7]  (256KB/batch)
//   E1 = exp(e_dst), E2 = exp(0.2 e_dst)   (per j)
//   ET = exp(-e_src), G = exp(0.8 e_src)   (per i)
// ---------------------------------------------------------------------------
__global__ __launch_bounds__(256) void k1_h_e(
    const float* __restrict__ X, const float* __restrict__ W,
    const float* __restrict__ A, const float* __restrict__ mask,
    unsigned short* __restrict__ hTt,
    float* __restrict__ E1, float* __restrict__ E2,
    float* __restrict__ ET, float* __restrict__ G) {
  __shared__ float WT[64][132];
  const int t = threadIdx.x;
  for (int idx = t; idx < 128 * 64; idx += 256) {
    int k = idx >> 6, d = idx & 63;
    WT[d][k] = W[idx];
  }
  __syncthreads();

  const int dg = t & 15;
  const int rp = t >> 4;
  const int gi0 = blockIdx.x * 32 + rp * 2;

  float a1[4], a2[4];
#pragma unroll
  for (int dd = 0; dd < 4; ++dd) {
    a1[dd] = A[dg + 16 * dd];
    a2[dd] = A[64 + dg + 16 * dd];
  }

  const float4* x0 = (const float4*)(X + (size_t)gi0 * 128);
  const float4* x1 = (const float4*)(X + (size_t)(gi0 + 1) * 128);
  float h0[4] = {0.f, 0.f, 0.f, 0.f}, h1[4] = {0.f, 0.f, 0.f, 0.f};
#pragma unroll 4
  for (int kq = 0; kq < 32; ++kq) {
    const float4 xa = x0[kq], xb = x1[kq];
#pragma unroll
    for (int dd = 0; dd < 4; ++dd) {
      const float4 w4 = *(const float4*)(&WT[dg + 16 * dd][kq * 4]);
      h0[dd] += xa.x * w4.x + xa.y * w4.y + xa.z * w4.z + xa.w * w4.w;
      h1[dd] += xb.x * w4.x + xb.y * w4.y + xb.z * w4.z + xb.w * w4.w;
    }
  }

  float es0 = 0.f, ed0 = 0.f, es1 = 0.f, ed1 = 0.f;
#pragma unroll
  for (int dd = 0; dd < 4; ++dd) {
    es0 += h0[dd] * a1[dd]; ed0 += h0[dd] * a2[dd];
    es1 += h1[dd] * a1[dd]; ed1 += h1[dd] * a2[dd];
  }
#pragma unroll
  for (int m = 1; m < 16; m <<= 1) {
    es0 += __shfl_xor(es0, m, 64);
    ed0 += __shfl_xor(ed0, m, 64);
    es1 += __shfl_xor(es1, m, 64);
    ed1 += __shfl_xor(ed1, m, 64);
  }
  if (dg == 0) {
    ET[gi0] = expf(-es0);      G[gi0] = expf(0.8f * es0);
    E1[gi0] = expf(ed0);       E2[gi0] = expf(0.2f * ed0);
    ET[gi0 + 1] = expf(-es1);  G[gi0 + 1] = expf(0.8f * es1);
    E1[gi0 + 1] = expf(ed1);   E2[gi0 + 1] = expf(0.2f * ed1);
  }

  const float m0 = mask[gi0], m1 = mask[gi0 + 1];
  const int b = gi0 >> 11, i = gi0 & 2047;
  const int ib = i >> 3, io = i & 7;
#pragma unroll
  for (int dd = 0; dd < 4; ++dd) {
    const int d = dg + 16 * dd;
    const uint32 lo = f2bf(h0[dd] * m0);
    const uint32 hi = f2bf(h1[dd] * m1);
    *(uint32*)(hTt + ((size_t)b << 17) + (ib << 9) + (d << 3) + io) = lo | (hi << 16);
  }
}

// ---------------------------------------------------------------------------
// K3: single streaming read of adj (128MB). (unchanged, measured ~26us)
// ---------------------------------------------------------------------------
__global__ __launch_bounds__(256) void k3_stats(
    const int* __restrict__ adj,
    const float* __restrict__ E1, const float* __restrict__ E2,
    const float* __restrict__ ET, const float* __restrict__ G,
    uint32* __restrict__ bitA, uint32* __restrict__ bitB,
    uint32* __restrict__ PP) {
  const int w = threadIdx.x >> 6, lane = threadIdx.x & 63;
  const int gi = blockIdx.x * 4 + w;
  const int b = gi >> 11, i = gi & 2047;
  const float eti = ET[gi];
  const int4* arow = (const int4*)(adj + (size_t)gi * 2048);
  const float4* e1p = (const float4*)(E1 + b * 2048);
  const float4* e2p = (const float4*)(E2 + b * 2048);
  float s1 = 0.f, s2 = 0.f;
#pragma unroll
  for (int jc = 0; jc < 8; ++jc) {
    const int idx = jc * 64 + lane;
    const int4 av = arow[idx];
    const float4 e1 = e1p[idx];
    const float4 e2 = e2p[idx];
    const bool m0 = (av.x == 1), m1b = (av.y == 1), m2 = (av.z == 1), m3 = (av.w == 1);
    const bool q0 = (e1.x > eti), q1 = (e1.y > eti), q2 = (e1.z > eti), q3 = (e1.w > eti);
    s1 += (m0 && q0) ? e1.x : 0.f;   s2 += (m0 && !q0) ? e2.x : 0.f;
    s1 += (m1b && q1) ? e1.y : 0.f;  s2 += (m1b && !q1) ? e2.y : 0.f;
    s1 += (m2 && q2) ? e1.z : 0.f;   s2 += (m2 && !q2) ? e2.z : 0.f;
    s1 += (m3 && q3) ? e1.w : 0.f;   s2 += (m3 && !q3) ? e2.w : 0.f;
    const u64 b0 = __ballot(m0), b1 = __ballot(m1b), b2 = __ballot(m2), b3 = __ballot(m3);
    if (lane < 4) {
      const u64 v = (lane == 0) ? b0 : (lane == 1) ? b1 : (lane == 2) ? b2 : b3;
      const size_t off = (size_t)(b * 32 + jc * 4 + lane) * 2048 + i;
      bitA[off] = (uint32)v;
      bitB[off] = (uint32)(v >> 32);
    }
  }
#pragma unroll
  for (int m = 1; m < 64; m <<= 1) {
    s1 += __shfl_xor(s1, m, 64);
    s2 += __shfl_xor(s2, m, 64);
  }
  if (lane == 0) {
    const float g = G[gi];
    const bool ok = (s1 + s2) > 0.f;
    const float p1 = ok ? 1.f / (s1 + s2 / g) : 0.f;
    const float p2 = ok ? 1.f / (s1 * g + s2) : 0.f;
    PP[gi] = (uint32)f2bf(p1) | ((uint32)f2bf(p2) << 16);
  }
}

// ---------------------------------------------------------------------------
// K4 (round-7 body, byte-exact): pe = bit ? max(P1_i*E1_j, P2_i*E2_j) : 0;
//   A-side register prefetch one kt ahead; B-side loaded in-iteration.
//   MEASUREMENT (round 9): grid 4096 instead of 1024; jt = (bid>>3)&127 so
//   each (b,jt) tile is computed by 4 blocks writing IDENTICAL bytes
//   (deterministic). k4's dispatch = 4x true cost -> rocprof top-1.
// ---------------------------------------------------------------------------
__global__ __launch_bounds__(256) void k4_fused(
    const unsigned short* __restrict__ hTt,
    const uint32* __restrict__ bitA, const uint32* __restrict__ bitB,
    const float* __restrict__ E1, const float* __restrict__ E2,
    const uint32* __restrict__ PP, float* __restrict__ out) {
  __shared__ float sAcc[3][16][68];
  const int t = threadIdx.x;
  const int w = t >> 6, l = t & 63;   // w = K-quarter
  const int bid = blockIdx.x;
  const int b = bid & 7;
  const int jt = (bid >> 3) & 127;    // 4-way duplicated (measurement)
  const int J0 = jt * 16;
  const int jj = J0 + (l & 15);
  const int kg = l >> 4;

  const float rE1 = E1[b * 2048 + jj];
  const float rE2 = E2[b * 2048 + jj];
  const int widx = ((jj >> 8) << 2) + (jj & 3);
  const size_t rowoff = (size_t)(b * 32 + widx) * 2048;
  const int sh = (jj >> 2) & 63;       // plane select uniform per 16-j tile
  const uint32 maskbit = 1u << (sh & 31);
  const uint32* bp = ((sh >= 32) ? bitB : bitA) + rowoff;
  const uint32* PPb = PP + b * 2048;
  const unsigned short* hTtb = hTt + ((size_t)b << 17);

  f32x4 acc[4] = {};

  // prologue: A-side loads for kt = 0
  const int ib0 = w * 512 + kg * 8;
  uint4 bq0 = *(const uint4*)(bp + ib0);
  uint4 bq1 = *(const uint4*)(bp + ib0 + 4);
  uint4 pq0 = *(const uint4*)(PPb + ib0);
  uint4 pq1 = *(const uint4*)(PPb + ib0 + 4);

#pragma unroll
  for (int kt = 0; kt < 16; ++kt) {
    const int i0 = w * 512 + kt * 32;

    // B-fragment loads for current kt (k-blocked hTt: 256B-contig / 16 lanes)
    const size_t bbase = ((size_t)((i0 >> 3) + kg)) << 9;
    const bf16x8 bv0 = *(const bf16x8*)(hTtb + bbase + (((l & 15) + 0) << 3));
    const bf16x8 bv1 = *(const bf16x8*)(hTtb + bbase + (((l & 15) + 16) << 3));
    const bf16x8 bv2 = *(const bf16x8*)(hTtb + bbase + (((l & 15) + 32) << 3));
    const bf16x8 bv3 = *(const bf16x8*)(hTtb + bbase + (((l & 15) + 48) << 3));

    // prefetch A-side for kt+1
    uint4 nbq0 = bq0, nbq1 = bq1, npq0 = pq0, npq1 = pq1;
    if (kt < 15) {
      const int ni = i0 + 32 + kg * 8;
      nbq0 = *(const uint4*)(bp + ni);
      nbq1 = *(const uint4*)(bp + ni + 4);
      npq0 = *(const uint4*)(PPb + ni);
      npq1 = *(const uint4*)(PPb + ni + 4);
    }

    // pe values from current A-side registers
    auto pv = [&](uint32 dw, uint32 pp) -> uint32 {
      const float p1f = __builtin_bit_cast(float, pp << 16);
      const float p2f = __builtin_bit_cast(float, pp & 0xFFFF0000u);
      const float v = fmaxf(p1f * rE1, p2f * rE2);
      return (dw & maskbit) ? __builtin_bit_cast(uint32, v) : 0u;
    };
    uint32 pe[8];
    pe[0] = pv(bq0.x, pq0.x);
    pe[1] = pv(bq0.y, pq0.y);
    pe[2] = pv(bq0.z, pq0.z);
    pe[3] = pv(bq0.w, pq0.w);
    pe[4] = pv(bq1.x, pq1.x);
    pe[5] = pv(bq1.y, pq1.y);
    pe[6] = pv(bq1.z, pq1.z);
    pe[7] = pv(bq1.w, pq1.w);

    union { uint32 u4[4]; bf16x8 v; } af;
#pragma unroll
    for (int e = 0; e < 4; ++e)  // truncating bf16 pair-pack
      af.u4[e] = (pe[2 * e + 1] & 0xFFFF0000u) | (pe[2 * e] >> 16);

    acc[0] = __builtin_amdgcn_mfma_f32_16x16x32_bf16(af.v, bv0, acc[0], 0, 0, 0);
    acc[1] = __builtin_amdgcn_mfma_f32_16x16x32_bf16(af.v, bv1, acc[1], 0, 0, 0);
    acc[2] = __builtin_amdgcn_mfma_f32_16x16x32_bf16(af.v, bv2, acc[2], 0, 0, 0);
    acc[3] = __builtin_amdgcn_mfma_f32_16x16x32_bf16(af.v, bv3, acc[3], 0, 0, 0);

    bq0 = nbq0; bq1 = nbq1; pq0 = npq0; pq1 = npq1;
  }

  // reduce across K-quarters + ELU.  C/D: col = l&15 (d), row = (l>>4)*4+r (j)
  if (w > 0) {
#pragma unroll
    for (int dt = 0; dt < 4; ++dt)
#pragma unroll
      for (int r = 0; r < 4; ++r)
        sAcc[w - 1][(l >> 4) * 4 + r][dt * 16 + (l & 15)] = acc[dt][r];
  }
  __syncthreads();
  if (w == 0) {
    float* outb = out + ((size_t)b << 17);
#pragma unroll
    for (int dt = 0; dt < 4; ++dt) {
#pragma unroll
      for (int r = 0; r < 4; ++r) {
        const int jrow = (l >> 4) * 4 + r;
        const int d = dt * 16 + (l & 15);
        float s = acc[dt][r] + sAcc[0][jrow][d] + sAcc[1][jrow][d] + sAcc[2][jrow][d];
        s = s > 0.f ? s : expm1f(s);
        outb[(size_t)(J0 + jrow) * 64 + d] = s;
      }
    }
  }
}

extern "C" void kernel_launch(void* const* d_in, const int* in_sizes, int n_in,
                              void* d_out, int out_size, void* d_ws, size_t ws_size,
                              hipStream_t stream) {
  const float* X = (const float*)d_in[0];     // [8,2048,128] f32
  const int* adj = (const int*)d_in[1];       // [8,2048,2048] i32
  const float* mask = (const float*)d_in[2];  // [8,2048] f32
  const float* W = (const float*)d_in[3];     // [128,64] f32
  const float* A = (const float*)d_in[4];     // [128,1] f32
  float* out = (float*)d_out;                 // [8,2048,64] f32
  char* ws = (char*)d_ws;

  unsigned short* hTt = (unsigned short*)(ws);  // 2 MB (k-blocked)
  float* E1 = (float*)(ws + 2097152);           // 64 KB each
  float* E2 = (float*)(ws + 2162688);
  float* ET = (float*)(ws + 2228224);
  float* G  = (float*)(ws + 2293760);
  uint32* PP = (uint32*)(ws + 2359296);         // 64 KB
  uint32* bitA = (uint32*)(ws + 2424832);       // 2 MB
  uint32* bitB = (uint32*)(ws + 4521984);       // 2 MB (ends 6619136)

  hipLaunchKernelGGL(k1_h_e, dim3(512), dim3(256), 0, stream, X, W, A, mask, hTt, E1, E2, ET, G);
  hipLaunchKernelGGL(k3_stats, dim3(4096), dim3(256), 0, stream, adj, E1, E2, ET, G, bitA, bitB, PP);
  // MEASUREMENT (round 9): 4x duplicated grid -> k4 dispatch = 4x true cost,
  // surfaces in rocprof top-5 with its own counters. Single k4 = dur/4.
  hipLaunchKernelGGL(k4_fused, dim3(4096), dim3(256), 0, stream, hTt, bitA, bitB, E1, E2, PP, out);
}

// Round 11
// 74.505 us; speedup vs baseline: 1.9906x; 1.9906x over previous
//
#include <hip/hip_runtime.h>
#include <stdint.h>

typedef unsigned int uint32;
typedef unsigned long long u64;
typedef short bf16x8 __attribute__((ext_vector_type(8)));
typedef float f32x4 __attribute__((ext_vector_type(4)));

// fp32 -> bf16 bits, round-to-nearest-even
__device__ __forceinline__ unsigned short f2bf(float f) {
  uint32 u = __builtin_bit_cast(uint32, f);
  u += 0x7FFFu + ((u >> 16) & 1u);
  return (unsigned short)(u >> 16);
}

// ---------------------------------------------------------------------------
// K1: h = X*W (16384x128 @ 128x64), e_src/e_dst = h.a, store
//   hTt : bf16, k-blocked layout [B][i>>3][d][i&7]  (256KB/batch)
//   E1 = exp(e_dst), E2 = exp(0.2 e_dst)   (per j)
//   ET = exp(-e_src), G = exp(0.8 e_src)   (per i)
// ---------------------------------------------------------------------------
__global__ __launch_bounds__(256) void k1_h_e(
    const float* __restrict__ X, const float* __restrict__ W,
    const float* __restrict__ A, const float* __restrict__ mask,
    unsigned short* __restrict__ hTt,
    float* __restrict__ E1, float* __restrict__ E2,
    float* __restrict__ ET, float* __restrict__ G) {
  __shared__ float WT[64][132];
  const int t = threadIdx.x;
  for (int idx = t; idx < 128 * 64; idx += 256) {
    int k = idx >> 6, d = idx & 63;
    WT[d][k] = W[idx];
  }
  __syncthreads();

  const int dg = t & 15;
  const int rp = t >> 4;
  const int gi0 = blockIdx.x * 32 + rp * 2;

  float a1[4], a2[4];
#pragma unroll
  for (int dd = 0; dd < 4; ++dd) {
    a1[dd] = A[dg + 16 * dd];
    a2[dd] = A[64 + dg + 16 * dd];
  }

  const float4* x0 = (const float4*)(X + (size_t)gi0 * 128);
  const float4* x1 = (const float4*)(X + (size_t)(gi0 + 1) * 128);
  float h0[4] = {0.f, 0.f, 0.f, 0.f}, h1[4] = {0.f, 0.f, 0.f, 0.f};
#pragma unroll 4
  for (int kq = 0; kq < 32; ++kq) {
    const float4 xa = x0[kq], xb = x1[kq];
#pragma unroll
    for (int dd = 0; dd < 4; ++dd) {
      const float4 w4 = *(const float4*)(&WT[dg + 16 * dd][kq * 4]);
      h0[dd] += xa.x * w4.x + xa.y * w4.y + xa.z * w4.z + xa.w * w4.w;
      h1[dd] += xb.x * w4.x + xb.y * w4.y + xb.z * w4.z + xb.w * w4.w;
    }
  }

  float es0 = 0.f, ed0 = 0.f, es1 = 0.f, ed1 = 0.f;
#pragma unroll
  for (int dd = 0; dd < 4; ++dd) {
    es0 += h0[dd] * a1[dd]; ed0 += h0[dd] * a2[dd];
    es1 += h1[dd] * a1[dd]; ed1 += h1[dd] * a2[dd];
  }
#pragma unroll
  for (int m = 1; m < 16; m <<= 1) {
    es0 += __shfl_xor(es0, m, 64);
    ed0 += __shfl_xor(ed0, m, 64);
    es1 += __shfl_xor(es1, m, 64);
    ed1 += __shfl_xor(ed1, m, 64);
  }
  if (dg == 0) {
    ET[gi0] = expf(-es0);      G[gi0] = expf(0.8f * es0);
    E1[gi0] = expf(ed0);       E2[gi0] = expf(0.2f * ed0);
    ET[gi0 + 1] = expf(-es1);  G[gi0 + 1] = expf(0.8f * es1);
    E1[gi0 + 1] = expf(ed1);   E2[gi0 + 1] = expf(0.2f * ed1);
  }

  const float m0 = mask[gi0], m1 = mask[gi0 + 1];
  const int b = gi0 >> 11, i = gi0 & 2047;
  const int ib = i >> 3, io = i & 7;
#pragma unroll
  for (int dd = 0; dd < 4; ++dd) {
    const int d = dg + 16 * dd;
    const uint32 lo = f2bf(h0[dd] * m0);
    const uint32 hi = f2bf(h1[dd] * m1);
    *(uint32*)(hTt + ((size_t)b << 17) + (ib << 9) + (d << 3) + io) = lo | (hi << 16);
  }
}

// ---------------------------------------------------------------------------
// K3: single streaming read of adj (128MB). (unchanged, measured ~26us)
// ---------------------------------------------------------------------------
__global__ __launch_bounds__(256) void k3_stats(
    const int* __restrict__ adj,
    const float* __restrict__ E1, const float* __restrict__ E2,
    const float* __restrict__ ET, const float* __restrict__ G,
    uint32* __restrict__ bitA, uint32* __restrict__ bitB,
    uint32* __restrict__ PP) {
  const int w = threadIdx.x >> 6, lane = threadIdx.x & 63;
  const int gi = blockIdx.x * 4 + w;
  const int b = gi >> 11, i = gi & 2047;
  const float eti = ET[gi];
  const int4* arow = (const int4*)(adj + (size_t)gi * 2048);
  const float4* e1p = (const float4*)(E1 + b * 2048);
  const float4* e2p = (const float4*)(E2 + b * 2048);
  float s1 = 0.f, s2 = 0.f;
#pragma unroll
  for (int jc = 0; jc < 8; ++jc) {
    const int idx = jc * 64 + lane;
    const int4 av = arow[idx];
    const float4 e1 = e1p[idx];
    const float4 e2 = e2p[idx];
    const bool m0 = (av.x == 1), m1b = (av.y == 1), m2 = (av.z == 1), m3 = (av.w == 1);
    const bool q0 = (e1.x > eti), q1 = (e1.y > eti), q2 = (e1.z > eti), q3 = (e1.w > eti);
    s1 += (m0 && q0) ? e1.x : 0.f;   s2 += (m0 && !q0) ? e2.x : 0.f;
    s1 += (m1b && q1) ? e1.y : 0.f;  s2 += (m1b && !q1) ? e2.y : 0.f;
    s1 += (m2 && q2) ? e1.z : 0.f;   s2 += (m2 && !q2) ? e2.z : 0.f;
    s1 += (m3 && q3) ? e1.w : 0.f;   s2 += (m3 && !q3) ? e2.w : 0.f;
    const u64 b0 = __ballot(m0), b1 = __ballot(m1b), b2 = __ballot(m2), b3 = __ballot(m3);
    if (lane < 4) {
      const u64 v = (lane == 0) ? b0 : (lane == 1) ? b1 : (lane == 2) ? b2 : b3;
      const size_t off = (size_t)(b * 32 + jc * 4 + lane) * 2048 + i;
      bitA[off] = (uint32)v;
      bitB[off] = (uint32)(v >> 32);
    }
  }
#pragma unroll
  for (int m = 1; m < 64; m <<= 1) {
    s1 += __shfl_xor(s1, m, 64);
    s2 += __shfl_xor(s2, m, 64);
  }
  if (lane == 0) {
    const float g = G[gi];
    const bool ok = (s1 + s2) > 0.f;
    const float p1 = ok ? 1.f / (s1 + s2 / g) : 0.f;
    const float p2 = ok ? 1.f / (s1 * g + s2) : 0.f;
    PP[gi] = (uint32)f2bf(p1) | ((uint32)f2bf(p2) << 16);
  }
}

// ---------------------------------------------------------------------------
// K4 v4: pe = bit ? max(P1_i*E1_j, P2_i*E2_j) : 0; MFMA over K.
//   Static 2-step software pipeline: TWO named register sets (A/B) for both
//   the A-side (bits/PP) and B-side (hTt fragments). Loads execute
//   unconditionally (kt+2 address wraps via &15 to valid-but-unused data) --
//   no conditional register carries, no swaps (round-8 miscompile avoided).
//   Each load has a full pe-gen+4xMFMA step (~160cy) to hide L2 latency.
// ---------------------------------------------------------------------------
__global__ __launch_bounds__(256) void k4_fused(
    const unsigned short* __restrict__ hTt,
    const uint32* __restrict__ bitA, const uint32* __restrict__ bitB,
    const float* __restrict__ E1, const float* __restrict__ E2,
    const uint32* __restrict__ PP, float* __restrict__ out) {
  __shared__ float sAcc[3][16][68];
  const int t = threadIdx.x;
  const int w = t >> 6, l = t & 63;   // w = K-quarter
  const int bid = blockIdx.x;
  const int b = bid & 7;
  const int jt = bid >> 3;            // 0..127
  const int J0 = jt * 16;
  const int jj = J0 + (l & 15);
  const int kg = l >> 4;

  const float rE1 = E1[b * 2048 + jj];
  const float rE2 = E2[b * 2048 + jj];
  const int widx = ((jj >> 8) << 2) + (jj & 3);
  const size_t rowoff = (size_t)(b * 32 + widx) * 2048;
  const int sh = (jj >> 2) & 63;       // plane select uniform per 16-j tile
  const uint32 maskbit = 1u << (sh & 31);
  const uint32* bp = ((sh >= 32) ? bitB : bitA) + rowoff;
  const uint32* PPb = PP + b * 2048;
  const unsigned short* hTtb = hTt + ((size_t)b << 17);

  f32x4 acc[4] = {};

  const int lane15_3 = (l & 15) << 3;

  // one pipeline step: pe-gen from given A-side regs + 4 MFMAs on B-side regs
  auto STEP = [&](const uint4& Xb0, const uint4& Xb1, const uint4& Xp0,
                  const uint4& Xp1, const bf16x8& Xv0, const bf16x8& Xv1,
                  const bf16x8& Xv2, const bf16x8& Xv3) {
    auto pv = [&](uint32 dw, uint32 pp) -> uint32 {
      const float p1f = __builtin_bit_cast(float, pp << 16);
      const float p2f = __builtin_bit_cast(float, pp & 0xFFFF0000u);
      const float v = fmaxf(p1f * rE1, p2f * rE2);
      return (dw & maskbit) ? __builtin_bit_cast(uint32, v) : 0u;
    };
    uint32 pe[8];
    pe[0] = pv(Xb0.x, Xp0.x);
    pe[1] = pv(Xb0.y, Xp0.y);
    pe[2] = pv(Xb0.z, Xp0.z);
    pe[3] = pv(Xb0.w, Xp0.w);
    pe[4] = pv(Xb1.x, Xp1.x);
    pe[5] = pv(Xb1.y, Xp1.y);
    pe[6] = pv(Xb1.z, Xp1.z);
    pe[7] = pv(Xb1.w, Xp1.w);
    union { uint32 u4[4]; bf16x8 v; } af;
#pragma unroll
    for (int e = 0; e < 4; ++e)  // truncating bf16 pair-pack
      af.u4[e] = (pe[2 * e + 1] & 0xFFFF0000u) | (pe[2 * e] >> 16);
    acc[0] = __builtin_amdgcn_mfma_f32_16x16x32_bf16(af.v, Xv0, acc[0], 0, 0, 0);
    acc[1] = __builtin_amdgcn_mfma_f32_16x16x32_bf16(af.v, Xv1, acc[1], 0, 0, 0);
    acc[2] = __builtin_amdgcn_mfma_f32_16x16x32_bf16(af.v, Xv2, acc[2], 0, 0, 0);
    acc[3] = __builtin_amdgcn_mfma_f32_16x16x32_bf16(af.v, Xv3, acc[3], 0, 0, 0);
  };

  // ---- prologue: load set A for kt = 0 ----
  const int i0a = w * 512;
  uint4 bq0a = *(const uint4*)(bp + i0a + kg * 8);
  uint4 bq1a = *(const uint4*)(bp + i0a + kg * 8 + 4);
  uint4 pq0a = *(const uint4*)(PPb + i0a + kg * 8);
  uint4 pq1a = *(const uint4*)(PPb + i0a + kg * 8 + 4);
  size_t bba = ((size_t)((i0a >> 3) + kg)) << 9;
  bf16x8 bv0a = *(const bf16x8*)(hTtb + bba + lane15_3);
  bf16x8 bv1a = *(const bf16x8*)(hTtb + bba + lane15_3 + (16 << 3));
  bf16x8 bv2a = *(const bf16x8*)(hTtb + bba + lane15_3 + (32 << 3));
  bf16x8 bv3a = *(const bf16x8*)(hTtb + bba + lane15_3 + (48 << 3));

#pragma unroll
  for (int kt = 0; kt < 16; kt += 2) {
    // load set B for kt+1 (kt+1 <= 15, always valid)
    const int i0b = w * 512 + (kt + 1) * 32;
    const uint4 bq0b = *(const uint4*)(bp + i0b + kg * 8);
    const uint4 bq1b = *(const uint4*)(bp + i0b + kg * 8 + 4);
    const uint4 pq0b = *(const uint4*)(PPb + i0b + kg * 8);
    const uint4 pq1b = *(const uint4*)(PPb + i0b + kg * 8 + 4);
    const size_t bbb = ((size_t)((i0b >> 3) + kg)) << 9;
    const bf16x8 bv0b = *(const bf16x8*)(hTtb + bbb + lane15_3);
    const bf16x8 bv1b = *(const bf16x8*)(hTtb + bbb + lane15_3 + (16 << 3));
    const bf16x8 bv2b = *(const bf16x8*)(hTtb + bbb + lane15_3 + (32 << 3));
    const bf16x8 bv3b = *(const bf16x8*)(hTtb + bbb + lane15_3 + (48 << 3));

    // compute kt with set A
    STEP(bq0a, bq1a, pq0a, pq1a, bv0a, bv1a, bv2a, bv3a);

    // load set A for kt+2 (wraps to 0 on last iter: valid address, unused)
    const int i0n = w * 512 + ((kt + 2) & 15) * 32;
    bq0a = *(const uint4*)(bp + i0n + kg * 8);
    bq1a = *(const uint4*)(bp + i0n + kg * 8 + 4);
    pq0a = *(const uint4*)(PPb + i0n + kg * 8);
    pq1a = *(const uint4*)(PPb + i0n + kg * 8 + 4);
    const size_t bbn = ((size_t)((i0n >> 3) + kg)) << 9;
    bv0a = *(const bf16x8*)(hTtb + bbn + lane15_3);
    bv1a = *(const bf16x8*)(hTtb + bbn + lane15_3 + (16 << 3));
    bv2a = *(const bf16x8*)(hTtb + bbn + lane15_3 + (32 << 3));
    bv3a = *(const bf16x8*)(hTtb + bbn + lane15_3 + (48 << 3));

    // compute kt+1 with set B
    STEP(bq0b, bq1b, pq0b, pq1b, bv0b, bv1b, bv2b, bv3b);
  }

  // reduce across K-quarters + ELU.  C/D: col = l&15 (d), row = (l>>4)*4+r (j)
  if (w > 0) {
#pragma unroll
    for (int dt = 0; dt < 4; ++dt)
#pragma unroll
      for (int r = 0; r < 4; ++r)
        sAcc[w - 1][(l >> 4) * 4 + r][dt * 16 + (l & 15)] = acc[dt][r];
  }
  __syncthreads();
  if (w == 0) {
    float* outb = out + ((size_t)b << 17);
#pragma unroll
    for (int dt = 0; dt < 4; ++dt) {
#pragma unroll
      for (int r = 0; r < 4; ++r) {
        const int jrow = (l >> 4) * 4 + r;
        const int d = dt * 16 + (l & 15);
        float s = acc[dt][r] + sAcc[0][jrow][d] + sAcc[1][jrow][d] + sAcc[2][jrow][d];
        s = s > 0.f ? s : expm1f(s);
        outb[(size_t)(J0 + jrow) * 64 + d] = s;
      }
    }
  }
}

extern "C" void kernel_launch(void* const* d_in, const int* in_sizes, int n_in,
                              void* d_out, int out_size, void* d_ws, size_t ws_size,
                              hipStream_t stream) {
  const float* X = (const float*)d_in[0];     // [8,2048,128] f32
  const int* adj = (const int*)d_in[1];       // [8,2048,2048] i32
  const float* mask = (const float*)d_in[2];  // [8,2048] f32
  const float* W = (const float*)d_in[3];     // [128,64] f32
  const float* A = (const float*)d_in[4];     // [128,1] f32
  float* out = (float*)d_out;                 // [8,2048,64] f32
  char* ws = (char*)d_ws;

  unsigned short* hTt = (unsigned short*)(ws);  // 2 MB (k-blocked)
  float* E1 = (float*)(ws + 2097152);           // 64 KB each
  float* E2 = (float*)(ws + 2162688);
  float* ET = (float*)(ws + 2228224);
  float* G  = (float*)(ws + 2293760);
  uint32* PP = (uint32*)(ws + 2359296);         // 64 KB
  uint32* bitA = (uint32*)(ws + 2424832);       // 2 MB
  uint32* bitB = (uint32*)(ws + 4521984);       // 2 MB (ends 6619136)

  hipLaunchKernelGGL(k1_h_e, dim3(512), dim3(256), 0, stream, X, W, A, mask, hTt, E1, E2, ET, G);
  hipLaunchKernelGGL(k3_stats, dim3(4096), dim3(256), 0, stream, adj, E1, E2, ET, G, bitA, bitB, PP);
  hipLaunchKernelGGL(k4_fused, dim3(1024), dim3(256), 0, stream, hTt, bitA, bitB, E1, E2, PP, out);
}

// Round 12
// 74.190 us; speedup vs baseline: 1.9991x; 1.0042x over previous
//
#include <hip/hip_runtime.h>
#include <stdint.h>

typedef unsigned int uint32;
typedef unsigned long long u64;
typedef short bf16x8 __attribute__((ext_vector_type(8)));
typedef float f32x4 __attribute__((ext_vector_type(4)));

// fp32 -> bf16 bits, round-to-nearest-even
__device__ __forceinline__ unsigned short f2bf(float f) {
  uint32 u = __builtin_bit_cast(uint32, f);
  u += 0x7FFFu + ((u >> 16) & 1u);
  return (unsigned short)(u >> 16);
}

// ---------------------------------------------------------------------------
// K1: h = X*W (16384x128 @ 128x64), e_src/e_dst = h.a, store
//   hTt : bf16, k-blocked layout [B][i>>3][d][i&7]  (256KB/batch)
//   E1 = exp(e_dst), E2 = exp(0.2 e_dst)   (per j)
//   ET = exp(-e_src), G = exp(0.8 e_src)   (per i)
// ---------------------------------------------------------------------------
__global__ __launch_bounds__(256) void k1_h_e(
    const float* __restrict__ X, const float* __restrict__ W,
    const float* __restrict__ A, const float* __restrict__ mask,
    unsigned short* __restrict__ hTt,
    float* __restrict__ E1, float* __restrict__ E2,
    float* __restrict__ ET, float* __restrict__ G) {
  __shared__ float WT[64][132];
  const int t = threadIdx.x;
  for (int idx = t; idx < 128 * 64; idx += 256) {
    int k = idx >> 6, d = idx & 63;
    WT[d][k] = W[idx];
  }
  __syncthreads();

  const int dg = t & 15;
  const int rp = t >> 4;
  const int gi0 = blockIdx.x * 32 + rp * 2;

  float a1[4], a2[4];
#pragma unroll
  for (int dd = 0; dd < 4; ++dd) {
    a1[dd] = A[dg + 16 * dd];
    a2[dd] = A[64 + dg + 16 * dd];
  }

  const float4* x0 = (const float4*)(X + (size_t)gi0 * 128);
  const float4* x1 = (const float4*)(X + (size_t)(gi0 + 1) * 128);
  float h0[4] = {0.f, 0.f, 0.f, 0.f}, h1[4] = {0.f, 0.f, 0.f, 0.f};
#pragma unroll 4
  for (int kq = 0; kq < 32; ++kq) {
    const float4 xa = x0[kq], xb = x1[kq];
#pragma unroll
    for (int dd = 0; dd < 4; ++dd) {
      const float4 w4 = *(const float4*)(&WT[dg + 16 * dd][kq * 4]);
      h0[dd] += xa.x * w4.x + xa.y * w4.y + xa.z * w4.z + xa.w * w4.w;
      h1[dd] += xb.x * w4.x + xb.y * w4.y + xb.z * w4.z + xb.w * w4.w;
    }
  }

  float es0 = 0.f, ed0 = 0.f, es1 = 0.f, ed1 = 0.f;
#pragma unroll
  for (int dd = 0; dd < 4; ++dd) {
    es0 += h0[dd] * a1[dd]; ed0 += h0[dd] * a2[dd];
    es1 += h1[dd] * a1[dd]; ed1 += h1[dd] * a2[dd];
  }
#pragma unroll
  for (int m = 1; m < 16; m <<= 1) {
    es0 += __shfl_xor(es0, m, 64);
    ed0 += __shfl_xor(ed0, m, 64);
    es1 += __shfl_xor(es1, m, 64);
    ed1 += __shfl_xor(ed1, m, 64);
  }
  if (dg == 0) {
    ET[gi0] = expf(-es0);      G[gi0] = expf(0.8f * es0);
    E1[gi0] = expf(ed0);       E2[gi0] = expf(0.2f * ed0);
    ET[gi0 + 1] = expf(-es1);  G[gi0 + 1] = expf(0.8f * es1);
    E1[gi0 + 1] = expf(ed1);   E2[gi0 + 1] = expf(0.2f * ed1);
  }

  const float m0 = mask[gi0], m1 = mask[gi0 + 1];
  const int b = gi0 >> 11, i = gi0 & 2047;
  const int ib = i >> 3, io = i & 7;
#pragma unroll
  for (int dd = 0; dd < 4; ++dd) {
    const int d = dg + 16 * dd;
    const uint32 lo = f2bf(h0[dd] * m0);
    const uint32 hi = f2bf(h1[dd] * m1);
    *(uint32*)(hTt + ((size_t)b << 17) + (ib << 9) + (d << 3) + io) = lo | (hi << 16);
  }
}

// ---------------------------------------------------------------------------
// K3: single streaming read of adj (128MB). (unchanged, measured ~26us)
// ---------------------------------------------------------------------------
__global__ __launch_bounds__(256) void k3_stats(
    const int* __restrict__ adj,
    const float* __restrict__ E1, const float* __restrict__ E2,
    const float* __restrict__ ET, const float* __restrict__ G,
    uint32* __restrict__ bitA, uint32* __restrict__ bitB,
    uint32* __restrict__ PP) {
  const int w = threadIdx.x >> 6, lane = threadIdx.x & 63;
  const int gi = blockIdx.x * 4 + w;
  const int b = gi >> 11, i = gi & 2047;
  const float eti = ET[gi];
  const int4* arow = (const int4*)(adj + (size_t)gi * 2048);
  const float4* e1p = (const float4*)(E1 + b * 2048);
  const float4* e2p = (const float4*)(E2 + b * 2048);
  float s1 = 0.f, s2 = 0.f;
#pragma unroll
  for (int jc = 0; jc < 8; ++jc) {
    const int idx = jc * 64 + lane;
    const int4 av = arow[idx];
    const float4 e1 = e1p[idx];
    const float4 e2 = e2p[idx];
    const bool m0 = (av.x == 1), m1b = (av.y == 1), m2 = (av.z == 1), m3 = (av.w == 1);
    const bool q0 = (e1.x > eti), q1 = (e1.y > eti), q2 = (e1.z > eti), q3 = (e1.w > eti);
    s1 += (m0 && q0) ? e1.x : 0.f;   s2 += (m0 && !q0) ? e2.x : 0.f;
    s1 += (m1b && q1) ? e1.y : 0.f;  s2 += (m1b && !q1) ? e2.y : 0.f;
    s1 += (m2 && q2) ? e1.z : 0.f;   s2 += (m2 && !q2) ? e2.z : 0.f;
    s1 += (m3 && q3) ? e1.w : 0.f;   s2 += (m3 && !q3) ? e2.w : 0.f;
    const u64 b0 = __ballot(m0), b1 = __ballot(m1b), b2 = __ballot(m2), b3 = __ballot(m3);
    if (lane < 4) {
      const u64 v = (lane == 0) ? b0 : (lane == 1) ? b1 : (lane == 2) ? b2 : b3;
      const size_t off = (size_t)(b * 32 + jc * 4 + lane) * 2048 + i;
      bitA[off] = (uint32)v;
      bitB[off] = (uint32)(v >> 32);
    }
  }
#pragma unroll
  for (int m = 1; m < 64; m <<= 1) {
    s1 += __shfl_xor(s1, m, 64);
    s2 += __shfl_xor(s2, m, 64);
  }
  if (lane == 0) {
    const float g = G[gi];
    const bool ok = (s1 + s2) > 0.f;
    const float p1 = ok ? 1.f / (s1 + s2 / g) : 0.f;
    const float p2 = ok ? 1.f / (s1 * g + s2) : 0.f;
    PP[gi] = (uint32)f2bf(p1) | ((uint32)f2bf(p2) << 16);
  }
}

// ---------------------------------------------------------------------------
// K4 v5 (= v4 body + __launch_bounds__(256, 4)):
//   Round-9 counters showed VGPR_Count=40 for a loop whose 2-deep pipeline
//   needs ~100 live regs: with no min-waves arg the compiler register-
//   allocated for 8 waves/EU (<=64 VGPR) and re-serialized all loads, even
//   though the 1024-block grid only ever gives 4 blocks/CU. Request 4
//   waves/EU explicitly -> 128-VGPR budget -> the pipeline can actually
//   keep 2 iterations of loads in flight.
// ---------------------------------------------------------------------------
__global__ __launch_bounds__(256, 4) void k4_fused(
    const unsigned short* __restrict__ hTt,
    const uint32* __restrict__ bitA, const uint32* __restrict__ bitB,
    const float* __restrict__ E1, const float* __restrict__ E2,
    const uint32* __restrict__ PP, float* __restrict__ out) {
  __shared__ float sAcc[3][16][68];
  const int t = threadIdx.x;
  const int w = t >> 6, l = t & 63;   // w = K-quarter
  const int bid = blockIdx.x;
  const int b = bid & 7;
  const int jt = bid >> 3;            // 0..127
  const int J0 = jt * 16;
  const int jj = J0 + (l & 15);
  const int kg = l >> 4;

  const float rE1 = E1[b * 2048 + jj];
  const float rE2 = E2[b * 2048 + jj];
  const int widx = ((jj >> 8) << 2) + (jj & 3);
  const size_t rowoff = (size_t)(b * 32 + widx) * 2048;
  const int sh = (jj >> 2) & 63;       // plane select uniform per 16-j tile
  const uint32 maskbit = 1u << (sh & 31);
  const uint32* bp = ((sh >= 32) ? bitB : bitA) + rowoff;
  const uint32* PPb = PP + b * 2048;
  const unsigned short* hTtb = hTt + ((size_t)b << 17);

  f32x4 acc[4] = {};

  const int lane15_3 = (l & 15) << 3;

  // one pipeline step: pe-gen from given A-side regs + 4 MFMAs on B-side regs
  auto STEP = [&](const uint4& Xb0, const uint4& Xb1, const uint4& Xp0,
                  const uint4& Xp1, const bf16x8& Xv0, const bf16x8& Xv1,
                  const bf16x8& Xv2, const bf16x8& Xv3) {
    auto pv = [&](uint32 dw, uint32 pp) -> uint32 {
      const float p1f = __builtin_bit_cast(float, pp << 16);
      const float p2f = __builtin_bit_cast(float, pp & 0xFFFF0000u);
      const float v = fmaxf(p1f * rE1, p2f * rE2);
      return (dw & maskbit) ? __builtin_bit_cast(uint32, v) : 0u;
    };
    uint32 pe[8];
    pe[0] = pv(Xb0.x, Xp0.x);
    pe[1] = pv(Xb0.y, Xp0.y);
    pe[2] = pv(Xb0.z, Xp0.z);
    pe[3] = pv(Xb0.w, Xp0.w);
    pe[4] = pv(Xb1.x, Xp1.x);
    pe[5] = pv(Xb1.y, Xp1.y);
    pe[6] = pv(Xb1.z, Xp1.z);
    pe[7] = pv(Xb1.w, Xp1.w);
    union { uint32 u4[4]; bf16x8 v; } af;
#pragma unroll
    for (int e = 0; e < 4; ++e)  // truncating bf16 pair-pack
      af.u4[e] = (pe[2 * e + 1] & 0xFFFF0000u) | (pe[2 * e] >> 16);
    acc[0] = __builtin_amdgcn_mfma_f32_16x16x32_bf16(af.v, Xv0, acc[0], 0, 0, 0);
    acc[1] = __builtin_amdgcn_mfma_f32_16x16x32_bf16(af.v, Xv1, acc[1], 0, 0, 0);
    acc[2] = __builtin_amdgcn_mfma_f32_16x16x32_bf16(af.v, Xv2, acc[2], 0, 0, 0);
    acc[3] = __builtin_amdgcn_mfma_f32_16x16x32_bf16(af.v, Xv3, acc[3], 0, 0, 0);
  };

  // ---- prologue: load set A for kt = 0 ----
  const int i0a = w * 512;
  uint4 bq0a = *(const uint4*)(bp + i0a + kg * 8);
  uint4 bq1a = *(const uint4*)(bp + i0a + kg * 8 + 4);
  uint4 pq0a = *(const uint4*)(PPb + i0a + kg * 8);
  uint4 pq1a = *(const uint4*)(PPb + i0a + kg * 8 + 4);
  size_t bba = ((size_t)((i0a >> 3) + kg)) << 9;
  bf16x8 bv0a = *(const bf16x8*)(hTtb + bba + lane15_3);
  bf16x8 bv1a = *(const bf16x8*)(hTtb + bba + lane15_3 + (16 << 3));
  bf16x8 bv2a = *(const bf16x8*)(hTtb + bba + lane15_3 + (32 << 3));
  bf16x8 bv3a = *(const bf16x8*)(hTtb + bba + lane15_3 + (48 << 3));

#pragma unroll
  for (int kt = 0; kt < 16; kt += 2) {
    // load set B for kt+1 (kt+1 <= 15, always valid)
    const int i0b = w * 512 + (kt + 1) * 32;
    const uint4 bq0b = *(const uint4*)(bp + i0b + kg * 8);
    const uint4 bq1b = *(const uint4*)(bp + i0b + kg * 8 + 4);
    const uint4 pq0b = *(const uint4*)(PPb + i0b + kg * 8);
    const uint4 pq1b = *(const uint4*)(PPb + i0b + kg * 8 + 4);
    const size_t bbb = ((size_t)((i0b >> 3) + kg)) << 9;
    const bf16x8 bv0b = *(const bf16x8*)(hTtb + bbb + lane15_3);
    const bf16x8 bv1b = *(const bf16x8*)(hTtb + bbb + lane15_3 + (16 << 3));
    const bf16x8 bv2b = *(const bf16x8*)(hTtb + bbb + lane15_3 + (32 << 3));
    const bf16x8 bv3b = *(const bf16x8*)(hTtb + bbb + lane15_3 + (48 << 3));

    // compute kt with set A
    STEP(bq0a, bq1a, pq0a, pq1a, bv0a, bv1a, bv2a, bv3a);

    // load set A for kt+2 (wraps to 0 on last iter: valid address, unused)
    const int i0n = w * 512 + ((kt + 2) & 15) * 32;
    bq0a = *(const uint4*)(bp + i0n + kg * 8);
    bq1a = *(const uint4*)(bp + i0n + kg * 8 + 4);
    pq0a = *(const uint4*)(PPb + i0n + kg * 8);
    pq1a = *(const uint4*)(PPb + i0n + kg * 8 + 4);
    const size_t bbn = ((size_t)((i0n >> 3) + kg)) << 9;
    bv0a = *(const bf16x8*)(hTtb + bbn + lane15_3);
    bv1a = *(const bf16x8*)(hTtb + bbn + lane15_3 + (16 << 3));
    bv2a = *(const bf16x8*)(hTtb + bbn + lane15_3 + (32 << 3));
    bv3a = *(const bf16x8*)(hTtb + bbn + lane15_3 + (48 << 3));

    // compute kt+1 with set B
    STEP(bq0b, bq1b, pq0b, pq1b, bv0b, bv1b, bv2b, bv3b);
  }

  // reduce across K-quarters + ELU.  C/D: col = l&15 (d), row = (l>>4)*4+r (j)
  if (w > 0) {
#pragma unroll
    for (int dt = 0; dt < 4; ++dt)
#pragma unroll
      for (int r = 0; r < 4; ++r)
        sAcc[w - 1][(l >> 4) * 4 + r][dt * 16 + (l & 15)] = acc[dt][r];
  }
  __syncthreads();
  if (w == 0) {
    float* outb = out + ((size_t)b << 17);
#pragma unroll
    for (int dt = 0; dt < 4; ++dt) {
#pragma unroll
      for (int r = 0; r < 4; ++r) {
        const int jrow = (l >> 4) * 4 + r;
        const int d = dt * 16 + (l & 15);
        float s = acc[dt][r] + sAcc[0][jrow][d] + sAcc[1][jrow][d] + sAcc[2][jrow][d];
        s = s > 0.f ? s : expm1f(s);
        outb[(size_t)(J0 + jrow) * 64 + d] = s;
      }
    }
  }
}

extern "C" void kernel_launch(void* const* d_in, const int* in_sizes, int n_in,
                              void* d_out, int out_size, void* d_ws, size_t ws_size,
                              hipStream_t stream) {
  const float* X = (const float*)d_in[0];     // [8,2048,128] f32
  const int* adj = (const int*)d_in[1];       // [8,2048,2048] i32
  const float* mask = (const float*)d_in[2];  // [8,2048] f32
  const float* W = (const float*)d_in[3];     // [128,64] f32
  const float* A = (const float*)d_in[4];     // [128,1] f32
  float* out = (float*)d_out;                 // [8,2048,64] f32
  char* ws = (char*)d_ws;

  unsigned short* hTt = (unsigned short*)(ws);  // 2 MB (k-blocked)
  float* E1 = (float*)(ws + 2097152);           // 64 KB each
  float* E2 = (float*)(ws + 2162688);
  float* ET = (float*)(ws + 2228224);
  float* G  = (float*)(ws + 2293760);
  uint32* PP = (uint32*)(ws + 2359296);         // 64 KB
  uint32* bitA = (uint32*)(ws + 2424832);       // 2 MB
  uint32* bitB = (uint32*)(ws + 4521984);       // 2 MB (ends 6619136)

  hipLaunchKernelGGL(k1_h_e, dim3(512), dim3(256), 0, stream, X, W, A, mask, hTt, E1, E2, ET, G);
  hipLaunchKernelGGL(k3_stats, dim3(4096), dim3(256), 0, stream, adj, E1, E2, ET, G, bitA, bitB, PP);
  hipLaunchKernelGGL(k4_fused, dim3(1024), dim3(256), 0, stream, hTt, bitA, bitB, E1, E2, PP, out);
}